// Round 2
// baseline (387.817 us; speedup 1.0000x reference)
//
#include <hip/hip_runtime.h>

#define NB 4
#define NC 19
#define NH 512
#define NW 1024
#define HW (NH * NW)
#define CHW (NC * HW)

#define TW 32
#define TH 8
#define HALO_W (TW + 2)           // 34
#define HALO_H (TH + 2)           // 10
#define NPX (HALO_W * HALO_H)     // 340

__launch_bounds__(256, 3)
__global__ void bdl_fused_kernel(const float* __restrict__ s_logits,
                                 const float* __restrict__ t_logits,
                                 float* __restrict__ out) {
    // probs for tile+halo, both tensors, all channels: 2*19*10*34*4 = 51,680 B
    __shared__ float sprob[2][NC][HALO_H][HALO_W];

    const int tid = threadIdx.x;
    const int h0 = blockIdx.y * TH;
    const int w0 = blockIdx.x * TW;
    const int b  = blockIdx.z;

    // ---- Phase 1: channel softmax for every tile+halo pixel, into LDS ----
    for (int idx = tid; idx < NPX; idx += 256) {
        const int py = idx / HALO_W;
        const int px = idx - py * HALO_W;
        const int h = h0 + py - 1;
        const int w = w0 + px - 1;
        const bool inb = (h >= 0) && (h < NH) && (w >= 0) && (w < NW);

        #pragma unroll
        for (int t = 0; t < 2; ++t) {
            const float* __restrict__ src = (t == 0) ? s_logits : t_logits;
            if (inb) {
                const float* __restrict__ p =
                    src + (size_t)b * CHW + (size_t)h * NW + (size_t)w;
                float v[NC];
                float m = -1e30f;
                #pragma unroll
                for (int c = 0; c < NC; ++c) {
                    v[c] = p[(size_t)c * HW];
                    m = fmaxf(m, v[c]);
                }
                float sum = 0.f;
                #pragma unroll
                for (int c = 0; c < NC; ++c) {
                    v[c] = __expf(v[c] - m);
                    sum += v[c];
                }
                const float r = 1.0f / sum;
                #pragma unroll
                for (int c = 0; c < NC; ++c)
                    sprob[t][c][py][px] = v[c] * r;
            } else {
                // zero padding outside the image (conv pad (1,1))
                #pragma unroll
                for (int c = 0; c < NC; ++c)
                    sprob[t][c][py][px] = 0.f;
            }
        }
    }
    __syncthreads();

    // ---- Phase 2: Sobel boundary + squared diff, accumulate per thread ----
    const int tx = tid & 31;   // 0..31 -> output col within tile
    const int ty = tid >> 5;   // 0..7  -> output row within tile
    float acc = 0.f;

    #pragma unroll 1
    for (int c = 0; c < NC; ++c) {
        float bnd[2];
        #pragma unroll
        for (int t = 0; t < 2; ++t) {
            // 3x3 patch around output pixel (halo coords: rows ty..ty+2, cols tx..tx+2)
            const float p00 = sprob[t][c][ty    ][tx    ];
            const float p01 = sprob[t][c][ty    ][tx + 1];
            const float p02 = sprob[t][c][ty    ][tx + 2];
            const float p10 = sprob[t][c][ty + 1][tx    ];
            const float p12 = sprob[t][c][ty + 1][tx + 2];
            const float p20 = sprob[t][c][ty + 2][tx    ];
            const float p21 = sprob[t][c][ty + 2][tx + 1];
            const float p22 = sprob[t][c][ty + 2][tx + 2];
            // Sobel X/Y (sign convention irrelevant under sqrt(gx^2+gy^2))
            const float gx = (p02 - p00) + 2.f * (p12 - p10) + (p22 - p20);
            const float gy = (p20 - p00) + 2.f * (p21 - p01) + (p22 - p02);
            bnd[t] = sqrtf(fmaf(gx, gx, gy * gy));
        }
        const float d = bnd[0] - bnd[1];
        acc = fmaf(d, d, acc);
    }

    // ---- Phase 3: block reduction + one atomic per block ----
    #pragma unroll
    for (int off = 32; off > 0; off >>= 1)
        acc += __shfl_down(acc, off, 64);

    __shared__ float wsum[4];
    if ((tid & 63) == 0) wsum[tid >> 6] = acc;
    __syncthreads();
    if (tid == 0) {
        const float s = wsum[0] + wsum[1] + wsum[2] + wsum[3];
        atomicAdd(out, s * (1.0f / (float)((size_t)NB * NC * NH * NW)));
    }
}

extern "C" void kernel_launch(void* const* d_in, const int* in_sizes, int n_in,
                              void* d_out, int out_size, void* d_ws, size_t ws_size,
                              hipStream_t stream) {
    const float* s_logits = (const float*)d_in[0];
    const float* t_logits = (const float*)d_in[1];
    float* out = (float*)d_out;

    // d_out is poisoned to 0xAA before every launch; zero it (graph-capture-safe)
    hipMemsetAsync(out, 0, sizeof(float), stream);

    dim3 grid(NW / TW, NH / TH, NB);   // 32 x 64 x 4 = 8192 blocks
    bdl_fused_kernel<<<grid, 256, 0, stream>>>(s_logits, t_logits, out);
}